// Round 12
// baseline (464.083 us; speedup 1.0000x reference)
//
#include <hip/hip_runtime.h>

// ---------- types ----------
using bf16x8 = __attribute__((ext_vector_type(8))) short;           // 8 bf16 (4 VGPR)
using u16x8  = __attribute__((ext_vector_type(8))) unsigned short;  // 16B staging
using f32x4  = __attribute__((ext_vector_type(4))) float;
using f32x4v = __attribute__((ext_vector_type(4))) float;

__device__ inline unsigned short f2bf(float f) {
  unsigned int u = __builtin_bit_cast(unsigned int, f);
  return (unsigned short)((u + 0x7fffu + ((u >> 16) & 1u)) >> 16);  // RNE
}
__device__ inline float bf2f(unsigned short h) {
  unsigned int u = ((unsigned int)h) << 16;
  return __builtin_bit_cast(float, u);
}

#define MFMA16(a, b, c) __builtin_amdgcn_mfma_f32_16x16x32_bf16((a), (b), (c), 0, 0, 0)

// LDS-visibility-only barrier: drains lgkmcnt but NOT vmcnt, so register-
// destined global prefetches stay in flight across the sync (v3-proven).
__device__ __forceinline__ void lds_barrier() {
  __builtin_amdgcn_sched_barrier(0);
  asm volatile("s_waitcnt lgkmcnt(0)" ::: "memory");
  __builtin_amdgcn_sched_barrier(0);
  __builtin_amdgcn_s_barrier();
  __builtin_amdgcn_sched_barrier(0);
}

// Problem constants
#define LL 4096
#define NB 4
#define DD 512
#define KDIM 128
#define OSZ ((size_t)NB * LL * DD)   // elements per output image

// ==========================================================================
// proj_qk (merged q+k): Out[b][l][128] = bf16( l2norm( X[l][b][:] @ Wk^T + bk ) )
// ==========================================================================
__global__ __launch_bounds__(256) void proj_qk_kernel(
    const float* __restrict__ Xq, const float* __restrict__ Xk,
    const float* __restrict__ Wk, const float* __restrict__ bk,
    unsigned short* __restrict__ Outq, unsigned short* __restrict__ Outk)
{
  __shared__ char smem[49152];                       // Xs 16KB | Ws 32KB
  char* Xs = smem;
  char* Ws = smem + 16384;

  const int tid = threadIdx.x;
  const int w = tid >> 6, lane = tid & 63, lr = lane & 15, g = lane >> 4;
  const int sel = blockIdx.x & 1;
  const float* X = sel ? Xk : Xq;
  unsigned short* Out = sel ? Outk : Outq;
  const int r0 = (blockIdx.x >> 1) * 64;

  f32x4 acc[8];
  #pragma unroll
  for (int nt = 0; nt < 8; ++nt) acc[nt] = f32x4{0.f, 0.f, 0.f, 0.f};

  for (int kc = 0; kc < 4; ++kc) {                   // K chunks of 128
    if (kc) __syncthreads();
    #pragma unroll
    for (int p = 0; p < 4; ++p) {
      int j = tid + p * 256;
      int row = j >> 4, e0 = (j & 15) * 8;
      const float* src = X + (size_t)(r0 + row) * DD + kc * 128 + e0;
      f32x4v f0 = *reinterpret_cast<const f32x4v*>(src);
      f32x4v f1 = *reinterpret_cast<const f32x4v*>(src + 4);
      u16x8 v;
      #pragma unroll
      for (int e = 0; e < 4; ++e) { v[e] = f2bf(f0[e]); v[e + 4] = f2bf(f1[e]); }
      *reinterpret_cast<u16x8*>(Xs + row * 256 + ((e0 * 2) ^ ((row & 7) << 4))) = v;
    }
    #pragma unroll
    for (int p = 0; p < 8; ++p) {
      int j = tid + p * 256;
      int n = j >> 4, e0 = (j & 15) * 8;
      const float* src = Wk + (size_t)n * DD + kc * 128 + e0;
      f32x4v f0 = *reinterpret_cast<const f32x4v*>(src);
      f32x4v f1 = *reinterpret_cast<const f32x4v*>(src + 4);
      u16x8 v;
      #pragma unroll
      for (int e = 0; e < 4; ++e) { v[e] = f2bf(f0[e]); v[e + 4] = f2bf(f1[e]); }
      *reinterpret_cast<u16x8*>(Ws + n * 256 + ((e0 * 2) ^ ((n & 7) << 4))) = v;
    }
    __syncthreads();
    const int arow = w * 16 + lr;
    #pragma unroll
    for (int ks = 0; ks < 4; ++ks) {
      int oa = (ks * 64 + g * 16) ^ ((arow & 7) << 4);
      bf16x8 a = *reinterpret_cast<const bf16x8*>(Xs + arow * 256 + oa);
      #pragma unroll
      for (int nt = 0; nt < 8; ++nt) {
        int n = nt * 16 + lr;
        int ob = (ks * 64 + g * 16) ^ ((n & 7) << 4);
        bf16x8 bb = *reinterpret_cast<const bf16x8*>(Ws + n * 256 + ob);
        acc[nt] = MFMA16(a, bb, acc[nt]);
      }
    }
  }

  float bias[8];
  #pragma unroll
  for (int nt = 0; nt < 8; ++nt) bias[nt] = bk[nt * 16 + lr];
  #pragma unroll
  for (int nt = 0; nt < 8; ++nt)
    #pragma unroll
    for (int i = 0; i < 4; ++i) acc[nt][i] += bias[nt];

  f32x4 ss = f32x4{0.f, 0.f, 0.f, 0.f};
  #pragma unroll
  for (int nt = 0; nt < 8; ++nt)
    #pragma unroll
    for (int i = 0; i < 4; ++i) ss[i] += acc[nt][i] * acc[nt][i];
  #pragma unroll
  for (int m = 1; m < 16; m <<= 1) {
    #pragma unroll
    for (int i = 0; i < 4; ++i) ss[i] += __shfl_xor(ss[i], m);
  }
  float inv[4];
  #pragma unroll
  for (int i = 0; i < 4; ++i) inv[i] = 1.0f / fmaxf(sqrtf(ss[i]), 1e-12f);

  #pragma unroll
  for (int nt = 0; nt < 8; ++nt) {
    int c = nt * 16 + lr;
    #pragma unroll
    for (int i = 0; i < 4; ++i) {
      int r = r0 + w * 16 + g * 4 + i;
      int l = r >> 2, b = r & 3;
      Out[((size_t)(b * LL + l)) * KDIM + c] = f2bf(acc[nt][i] * inv[i]);
    }
  }
}

// ==========================================================================
// proj_v: Vt[b][d][s] = bf16( value[s][b][:] @ Wv^T + bv )   (transposed store)
// ==========================================================================
__global__ __launch_bounds__(256) void proj_v_kernel(
    const float* __restrict__ X, const float* __restrict__ Wv,
    const float* __restrict__ bv, unsigned short* __restrict__ VtOut)
{
  __shared__ char smem[40960];
  char* Xs = smem;
  char* Ws = smem + 32768;

  const int tid = threadIdx.x;
  const int w = tid >> 6, lane = tid & 63, lr = lane & 15, g = lane >> 4;
  const int rb = blockIdx.x >> 3, nb = blockIdx.x & 7;
  const int r0 = rb * 256, d0 = nb * 64;

  f32x4 acc[4][4];
  #pragma unroll
  for (int rt = 0; rt < 4; ++rt)
    #pragma unroll
    for (int nt = 0; nt < 4; ++nt) acc[rt][nt] = f32x4{0.f, 0.f, 0.f, 0.f};

  for (int kc = 0; kc < 8; ++kc) {
    if (kc) __syncthreads();
    #pragma unroll
    for (int p = 0; p < 8; ++p) {
      int j = tid + p * 256;
      int row = j >> 3, e0 = (j & 7) * 8;
      const float* src = X + (size_t)(r0 + row) * DD + kc * 64 + e0;
      f32x4v f0 = *reinterpret_cast<const f32x4v*>(src);
      f32x4v f1 = *reinterpret_cast<const f32x4v*>(src + 4);
      u16x8 v;
      #pragma unroll
      for (int e = 0; e < 4; ++e) { v[e] = f2bf(f0[e]); v[e + 4] = f2bf(f1[e]); }
      *reinterpret_cast<u16x8*>(Xs + row * 128 + ((e0 * 2) ^ ((row & 7) << 4))) = v;
    }
    #pragma unroll
    for (int p = 0; p < 2; ++p) {
      int j = tid + p * 256;
      int n = j >> 3, e0 = (j & 7) * 8;
      const float* src = Wv + (size_t)(d0 + n) * DD + kc * 64 + e0;
      f32x4v f0 = *reinterpret_cast<const f32x4v*>(src);
      f32x4v f1 = *reinterpret_cast<const f32x4v*>(src + 4);
      u16x8 v;
      #pragma unroll
      for (int e = 0; e < 4; ++e) { v[e] = f2bf(f0[e]); v[e + 4] = f2bf(f1[e]); }
      *reinterpret_cast<u16x8*>(Ws + n * 128 + ((e0 * 2) ^ ((n & 7) << 4))) = v;
    }
    __syncthreads();
    #pragma unroll
    for (int ks = 0; ks < 2; ++ks) {
      bf16x8 a[4];
      #pragma unroll
      for (int rt = 0; rt < 4; ++rt) {
        int arow = w * 64 + rt * 16 + lr;
        a[rt] = *reinterpret_cast<const bf16x8*>(
            Xs + arow * 128 + ((ks * 64 + g * 16) ^ ((arow & 7) << 4)));
      }
      #pragma unroll
      for (int nt = 0; nt < 4; ++nt) {
        int n = nt * 16 + lr;
        bf16x8 bb = *reinterpret_cast<const bf16x8*>(
            Ws + n * 128 + ((ks * 64 + g * 16) ^ ((n & 7) << 4)));
        #pragma unroll
        for (int rt = 0; rt < 4; ++rt) acc[rt][nt] = MFMA16(a[rt], bb, acc[rt][nt]);
      }
    }
  }

  __syncthreads();
  float bias[4];
  #pragma unroll
  for (int nt = 0; nt < 4; ++nt) bias[nt] = bv[d0 + nt * 16 + lr];

  unsigned short* Ts = (unsigned short*)smem;
  #pragma unroll
  for (int rt = 0; rt < 4; ++rt)
    #pragma unroll
    for (int nt = 0; nt < 4; ++nt) {
      int dl = nt * 16 + lr;
      #pragma unroll
      for (int i = 0; i < 4; ++i) {
        int rl = w * 64 + rt * 16 + g * 4 + i;
        Ts[dl * 256 + (rl ^ ((dl & 31) << 1))] = f2bf(acc[rt][nt][i] + bias[nt]);
      }
    }
  __syncthreads();

  int bsel = tid >> 6, dl = tid & 63;
  int l0 = r0 >> 2;
  #pragma unroll
  for (int jj = 0; jj < 8; ++jj) {
    u16x8 v;
    #pragma unroll
    for (int e = 0; e < 8; ++e) {
      int rl = (jj * 8 + e) * 4 + bsel;
      v[e] = Ts[dl * 256 + (rl ^ ((dl & 31) << 1))];
    }
    *reinterpret_cast<u16x8*>(VtOut + ((size_t)(bsel * DD + d0 + dl)) * LL + l0 + jj * 8) = v;
  }
}

// ==========================================================================
// attn v12: v3's EXACT step, s-split into 2 halves -> grid 512 -> 2 genuinely
// independent barrier domains per CU (co-resident pair shares batch+s-half,
// different q-tiles -> shared K/V stream in L2, aggregate traffic unchanged).
// Cross-block combine: both blocks write bf16 unnormalized partials + f32
// row-sums to ws; per-pair atomic counter; SECOND finisher combines (both
// sides bf16-rounded -> order-symmetric -> deterministic) and writes Out.
// ==========================================================================
#define QBLK 64
#define KBLK 64
#define NHALF 32          // steps per block (2048 s each)

__device__ __forceinline__ void attn_step(
    int kt1, const unsigned short* __restrict__ Kp,
    const unsigned short* __restrict__ Vp,
    const char* kcur, char* knxt, char* pcur,
    const bf16x8 (&qf)[4], bf16x8 (&vcur)[8], bf16x8 (&vnxt)[8],
    f32x4 (&acc)[4][4], float (&lsum)[4],
    int lr, int g, int w, int wq, int ws, int r0k, int c0k)
{
  // ---- prefetch K(t+1) -> regs (issued first: oldest vmcnt) ----
  u16x8 kpr0 = *reinterpret_cast<const u16x8*>(
      Kp + (size_t)(kt1 * KBLK + r0k) * KDIM + c0k);
  u16x8 kpr1 = *reinterpret_cast<const u16x8*>(
      Kp + (size_t)(kt1 * KBLK + r0k + 32) * KDIM + c0k);
  // ---- prefetch V(t+1) -> regs ----
  #pragma unroll
  for (int u = 0; u < 8; ++u) {
    int ks = u >> 2, ch = u & 3;
    vnxt[u] = *reinterpret_cast<const bf16x8*>(
        Vp + (size_t)(w * 64 + ch * 16 + lr) * LL + kt1 * KBLK + ks * 32 + g * 8);
  }

  // ---- S phase: 16 q x 32 s from Ks[cur] ----
  f32x4 s0 = f32x4{0.f, 0.f, 0.f, 0.f};
  f32x4 s1 = f32x4{0.f, 0.f, 0.f, 0.f};
  const int sr0 = ws * 32 + lr, sr1 = sr0 + 16;
  #pragma unroll
  for (int kc = 0; kc < 4; ++kc) {
    bf16x8 kb0 = *reinterpret_cast<const bf16x8*>(
        kcur + sr0 * 256 + ((kc * 64 + g * 16) ^ ((sr0 & 7) << 4)));
    bf16x8 kb1 = *reinterpret_cast<const bf16x8*>(
        kcur + sr1 * 256 + ((kc * 64 + g * 16) ^ ((sr1 & 7) << 4)));
    s0 = MFMA16(qf[kc], kb0, s0);
    s1 = MFMA16(qf[kc], kb1, s1);
  }

  // ---- softmax numerator (fixed max 31) + P write ----
  #pragma unroll
  for (int i = 0; i < 4; ++i) {
    float p0 = exp2f(fmaf(s0[i], 43.280851f, -44.723546f));
    float p1 = exp2f(fmaf(s1[i], 43.280851f, -44.723546f));
    lsum[i] += p0 + p1;
    int q = wq * 16 + g * 4 + i;
    int swz = (q & 7) << 4;
    *(unsigned short*)(pcur + q * 128 + ((sr0 * 2) ^ swz)) = f2bf(p0);
    *(unsigned short*)(pcur + q * 128 + ((sr1 * 2) ^ swz)) = f2bf(p1);
  }

  // ---- write K(t+1) regs -> other LDS buffer (counted vmcnt; V in flight) ----
  {
    int swz = (r0k & 7) << 4;
    *reinterpret_cast<u16x8*>(knxt + r0k * 256 + ((c0k * 2) ^ swz)) = kpr0;
    *reinterpret_cast<u16x8*>(knxt + (r0k + 32) * 256 + ((c0k * 2) ^ swz)) = kpr1;
  }

  lds_barrier();   // LDS-only drain; V prefetch stays in flight

  // ---- PV phase: all 64 q x this wave's 64-wide d slice ----
  #pragma unroll
  for (int qt = 0; qt < 4; ++qt) {
    int q = qt * 16 + lr;
    int swz = (q & 7) << 4;
    bf16x8 pa0 = *reinterpret_cast<const bf16x8*>(pcur + q * 128 + ((g * 16) ^ swz));
    bf16x8 pa1 = *reinterpret_cast<const bf16x8*>(pcur + q * 128 + ((64 + g * 16) ^ swz));
    #pragma unroll
    for (int ch = 0; ch < 4; ++ch) {
      acc[qt][ch] = MFMA16(pa0, vcur[ch], acc[qt][ch]);
      acc[qt][ch] = MFMA16(pa1, vcur[4 + ch], acc[qt][ch]);
    }
  }
}

__global__ __launch_bounds__(512, 2) void attn_kernel(
    const unsigned short* __restrict__ Qn, const unsigned short* __restrict__ Kn,
    const unsigned short* __restrict__ Vt,
    unsigned short* __restrict__ Opart, float* __restrict__ lpart,
    int* __restrict__ cnt, float* __restrict__ Out)
{
  __shared__ char smem[49664];
  char* Ks0 = smem;                                  // [64 s][128 k] bf16, 16KB
  char* Ks1 = smem + 16384;
  char* Ps0 = smem + 32768;                          // [64 q][64 s] bf16, 8KB
  char* Ps1 = smem + 40960;
  float* Ls = (float*)(smem + 49152);                // [2][64] partial row sums
  __shared__ int role_sh;

  const int tid = threadIdx.x;
  const int w = tid >> 6, lane = tid & 63, lr = lane & 15, g = lane >> 4;
  const int wq = w & 3, ws = w >> 2;
  const int r0k = tid >> 4, c0k = (tid & 15) * 8;    // K staging mapping

  // bid -> (batch, s-half, q-tile). XCD x serves (b = x>>1, sh = x&1);
  // co-resident pair (bid, bid+256) shares (b, sh) -> L2-shared K/V stream.
  const int bid = blockIdx.x;
  const int b = (bid & 7) >> 1;
  const int sh = bid & 1;
  const int qt = bid >> 3;                           // 0..63
  const int q0 = qt * QBLK;
  const int pairid = b * 64 + qt;                    // 0..255

  const unsigned short* Kp = Kn + (size_t)b * LL * KDIM + (size_t)sh * 2048 * KDIM;
  const unsigned short* Vp = Vt + (size_t)b * DD * LL + sh * 2048;

  // Q A-fragments (KD=128 -> 4 chunks of 32)
  bf16x8 qf[4];
  {
    const unsigned short* qp = Qn + ((size_t)(b * LL + q0 + wq * 16 + lr)) * KDIM + g * 8;
    #pragma unroll
    for (int kc = 0; kc < 4; ++kc)
      qf[kc] = *reinterpret_cast<const bf16x8*>(qp + kc * 32);
  }

  f32x4 acc[4][4];
  #pragma unroll
  for (int qt4 = 0; qt4 < 4; ++qt4)
    #pragma unroll
    for (int ch = 0; ch < 4; ++ch) acc[qt4][ch] = f32x4{0.f, 0.f, 0.f, 0.f};
  float lsum[4] = {0.f, 0.f, 0.f, 0.f};

  bf16x8 vbA[8], vbB[8];

  // ---- prologue: K(0) -> Ks0, V(0) -> vbA ----
  {
    u16x8 k0 = *reinterpret_cast<const u16x8*>(Kp + (size_t)r0k * KDIM + c0k);
    u16x8 k1 = *reinterpret_cast<const u16x8*>(Kp + (size_t)(r0k + 32) * KDIM + c0k);
    int swz = (r0k & 7) << 4;
    *reinterpret_cast<u16x8*>(Ks0 + r0k * 256 + ((c0k * 2) ^ swz)) = k0;
    *reinterpret_cast<u16x8*>(Ks0 + (r0k + 32) * 256 + ((c0k * 2) ^ swz)) = k1;
    #pragma unroll
    for (int u = 0; u < 8; ++u) {
      int ks = u >> 2, ch = u & 3;
      vbA[u] = *reinterpret_cast<const bf16x8*>(
          Vp + (size_t)(w * 64 + ch * 16 + lr) * LL + ks * 32 + g * 8);
    }
  }
  __syncthreads();

  // ---- main loop, 2 steps per iter (static buffer/reg naming), 32 steps ----
  for (int t = 0; t < NHALF; t += 2) {
    int k1i = (t + 1 < NHALF) ? t + 1 : NHALF - 1;
    int k2i = (t + 2 < NHALF) ? t + 2 : NHALF - 1;
    attn_step(k1i, Kp, Vp, Ks0, Ks1, Ps0, qf, vbA, vbB, acc, lsum,
              lr, g, w, wq, ws, r0k, c0k);
    attn_step(k2i, Kp, Vp, Ks1, Ks0, Ps1, qf, vbB, vbA, acc, lsum,
              lr, g, w, wq, ws, r0k, c0k);
  }

  // ---- combine partial row sums across the two s-subtiles of this block ----
  #pragma unroll
  for (int m = 1; m < 16; m <<= 1) {
    #pragma unroll
    for (int i = 0; i < 4; ++i) lsum[i] += __shfl_xor(lsum[i], m);
  }
  if (lr == 0) {
    #pragma unroll
    for (int i = 0; i < 4; ++i) Ls[ws * 64 + wq * 16 + g * 4 + i] = lsum[i];
  }
  __syncthreads();

  // ==== cross-block combine (two-slot, last-finisher reduces) ====
  unsigned short* myO = Opart + (size_t)sh * OSZ;
  #pragma unroll
  for (int qt4 = 0; qt4 < 4; ++qt4)
    #pragma unroll
    for (int ch = 0; ch < 4; ++ch) {
      int d = w * 64 + ch * 16 + lr;
      #pragma unroll
      for (int i = 0; i < 4; ++i) {
        int q = q0 + qt4 * 16 + g * 4 + i;
        myO[((size_t)q * NB + b) * DD + d] = f2bf(acc[qt4][ch][i]);
      }
    }
  if (tid < 64) lpart[(pairid * 2 + sh) * 64 + tid] = Ls[tid] + Ls[64 + tid];
  __threadfence();
  __syncthreads();
  if (tid == 0) role_sh = atomicAdd(&cnt[pairid], 1);
  __syncthreads();
  if (role_sh == 0) return;          // first finisher: partial published, done
  __threadfence();                   // acquire side

  const unsigned short* poO = Opart + (size_t)(sh ^ 1) * OSZ;
  const float* plp = lpart + (pairid * 2 + (sh ^ 1)) * 64;
  #pragma unroll
  for (int qt4 = 0; qt4 < 4; ++qt4) {
    float linv[4];
    #pragma unroll
    for (int i = 0; i < 4; ++i) {
      int ql = qt4 * 16 + g * 4 + i;
      linv[i] = 1.0f / ((Ls[ql] + Ls[64 + ql]) + plp[ql]);
    }
    #pragma unroll
    for (int ch = 0; ch < 4; ++ch) {
      int d = w * 64 + ch * 16 + lr;
      #pragma unroll
      for (int i = 0; i < 4; ++i) {
        int q = q0 + qt4 * 16 + g * 4 + i;
        size_t idx = ((size_t)q * NB + b) * DD + d;
        // both contributions bf16-rounded -> order-symmetric -> deterministic
        float mine = bf2f(f2bf(acc[qt4][ch][i]));
        float po = bf2f(poO[idx]);
        Out[idx] = (mine + po) * linv[i];
      }
    }
  }
}

// ==========================================================================
extern "C" void kernel_launch(void* const* d_in, const int* in_sizes, int n_in,
                              void* d_out, int out_size, void* d_ws, size_t ws_size,
                              hipStream_t stream) {
  const float* query = (const float*)d_in[0];
  const float* key   = (const float*)d_in[1];
  const float* value = (const float*)d_in[2];
  const float* WKw   = (const float*)d_in[3];
  const float* WKb   = (const float*)d_in[4];
  const float* WVw   = (const float*)d_in[5];
  const float* WVb   = (const float*)d_in[6];
  float* out = (float*)d_out;

  unsigned short* wqn = (unsigned short*)d_ws;            // [4][4096][128] bf16, 4MB
  unsigned short* wkn = wqn + (size_t)NB * LL * KDIM;     // 4MB
  unsigned short* vt  = wkn + (size_t)NB * LL * KDIM;     // [4][512][4096] bf16, 16.8MB
  unsigned short* opart = vt + (size_t)NB * DD * LL;      // 2 x [4][4096][512] bf16, 33.6MB
  float* lpart = (float*)(opart + 2 * OSZ);               // [256][2][64] f32, 128KB
  int* cnt = (int*)(lpart + 256 * 2 * 64);                // [256] int

  hipMemsetAsync(cnt, 0, 256 * sizeof(int), stream);
  proj_qk_kernel<<<512, 256, 0, stream>>>(query, key, WKw, WKb, wqn, wkn);
  proj_v_kernel <<<512, 256, 0, stream>>>(value, WVw, WVb, vt);
  attn_kernel   <<<512, 512, 0, stream>>>(wqn, wkn, vt, opart, lpart, cnt, out);
}

// Round 13
// 209.394 us; speedup vs baseline: 2.2163x; 2.2163x over previous
//
#include <hip/hip_runtime.h>

// ---------- types ----------
using bf16x8 = __attribute__((ext_vector_type(8))) short;           // 8 bf16 (4 VGPR)
using u16x8  = __attribute__((ext_vector_type(8))) unsigned short;  // 16B staging
using f32x4  = __attribute__((ext_vector_type(4))) float;
using f32x4v = __attribute__((ext_vector_type(4))) float;

__device__ inline unsigned short f2bf(float f) {
  unsigned int u = __builtin_bit_cast(unsigned int, f);
  return (unsigned short)((u + 0x7fffu + ((u >> 16) & 1u)) >> 16);  // RNE
}

#define MFMA16(a, b, c) __builtin_amdgcn_mfma_f32_16x16x32_bf16((a), (b), (c), 0, 0, 0)

// LDS-visibility-only barrier: drains lgkmcnt but NOT vmcnt, so register-
// destined global prefetches stay in flight across the sync (v3-proven).
__device__ __forceinline__ void lds_barrier() {
  __builtin_amdgcn_sched_barrier(0);
  asm volatile("s_waitcnt lgkmcnt(0)" ::: "memory");
  __builtin_amdgcn_sched_barrier(0);
  __builtin_amdgcn_s_barrier();
  __builtin_amdgcn_sched_barrier(0);
}

// Problem constants
#define LL 4096
#define NB 4
#define DD 512
#define KDIM 128

// ==========================================================================
// proj_qk body: Out[b][l][128] = bf16( l2norm( X[l][b][:] @ Wk^T + bk ) )
// 64-row tile, 4 waves. (unchanged, proven)
// ==========================================================================
__device__ __forceinline__ void proj_qk_body(
    char* smem, int bid, const float* __restrict__ Xq, const float* __restrict__ Xk,
    const float* __restrict__ Wk, const float* __restrict__ bk,
    unsigned short* __restrict__ Outq, unsigned short* __restrict__ Outk)
{
  char* Xs = smem;
  char* Ws = smem + 16384;

  const int tid = threadIdx.x;
  const int w = tid >> 6, lane = tid & 63, lr = lane & 15, g = lane >> 4;
  const int sel = bid & 1;
  const float* X = sel ? Xk : Xq;
  unsigned short* Out = sel ? Outk : Outq;
  const int r0 = (bid >> 1) * 64;

  f32x4 acc[8];
  #pragma unroll
  for (int nt = 0; nt < 8; ++nt) acc[nt] = f32x4{0.f, 0.f, 0.f, 0.f};

  for (int kc = 0; kc < 4; ++kc) {                   // K chunks of 128
    if (kc) __syncthreads();
    #pragma unroll
    for (int p = 0; p < 4; ++p) {
      int j = tid + p * 256;
      int row = j >> 4, e0 = (j & 15) * 8;
      const float* src = X + (size_t)(r0 + row) * DD + kc * 128 + e0;
      f32x4v f0 = *reinterpret_cast<const f32x4v*>(src);
      f32x4v f1 = *reinterpret_cast<const f32x4v*>(src + 4);
      u16x8 v;
      #pragma unroll
      for (int e = 0; e < 4; ++e) { v[e] = f2bf(f0[e]); v[e + 4] = f2bf(f1[e]); }
      *reinterpret_cast<u16x8*>(Xs + row * 256 + ((e0 * 2) ^ ((row & 7) << 4))) = v;
    }
    #pragma unroll
    for (int p = 0; p < 8; ++p) {
      int j = tid + p * 256;
      int n = j >> 4, e0 = (j & 15) * 8;
      const float* src = Wk + (size_t)n * DD + kc * 128 + e0;
      f32x4v f0 = *reinterpret_cast<const f32x4v*>(src);
      f32x4v f1 = *reinterpret_cast<const f32x4v*>(src + 4);
      u16x8 v;
      #pragma unroll
      for (int e = 0; e < 4; ++e) { v[e] = f2bf(f0[e]); v[e + 4] = f2bf(f1[e]); }
      *reinterpret_cast<u16x8*>(Ws + n * 256 + ((e0 * 2) ^ ((n & 7) << 4))) = v;
    }
    __syncthreads();
    const int arow = w * 16 + lr;
    #pragma unroll
    for (int ks = 0; ks < 4; ++ks) {
      int oa = (ks * 64 + g * 16) ^ ((arow & 7) << 4);
      bf16x8 a = *reinterpret_cast<const bf16x8*>(Xs + arow * 256 + oa);
      #pragma unroll
      for (int nt = 0; nt < 8; ++nt) {
        int n = nt * 16 + lr;
        int ob = (ks * 64 + g * 16) ^ ((n & 7) << 4);
        bf16x8 bb = *reinterpret_cast<const bf16x8*>(Ws + n * 256 + ob);
        acc[nt] = MFMA16(a, bb, acc[nt]);
      }
    }
  }

  float bias[8];
  #pragma unroll
  for (int nt = 0; nt < 8; ++nt) bias[nt] = bk[nt * 16 + lr];
  #pragma unroll
  for (int nt = 0; nt < 8; ++nt)
    #pragma unroll
    for (int i = 0; i < 4; ++i) acc[nt][i] += bias[nt];

  f32x4 ss = f32x4{0.f, 0.f, 0.f, 0.f};
  #pragma unroll
  for (int nt = 0; nt < 8; ++nt)
    #pragma unroll
    for (int i = 0; i < 4; ++i) ss[i] += acc[nt][i] * acc[nt][i];
  #pragma unroll
  for (int m = 1; m < 16; m <<= 1) {
    #pragma unroll
    for (int i = 0; i < 4; ++i) ss[i] += __shfl_xor(ss[i], m);
  }
  float inv[4];
  #pragma unroll
  for (int i = 0; i < 4; ++i) inv[i] = 1.0f / fmaxf(sqrtf(ss[i]), 1e-12f);

  #pragma unroll
  for (int nt = 0; nt < 8; ++nt) {
    int c = nt * 16 + lr;
    #pragma unroll
    for (int i = 0; i < 4; ++i) {
      int r = r0 + w * 16 + g * 4 + i;
      int l = r >> 2, b = r & 3;
      Out[((size_t)(b * LL + l)) * KDIM + c] = f2bf(acc[nt][i] * inv[i]);
    }
  }
}

// ==========================================================================
// proj_v body: Vt[b][d][s] = bf16( value[s][b][:] @ Wv^T + bv ) (transposed)
// 256-row x 64-col tile. (unchanged, proven)
// ==========================================================================
__device__ __forceinline__ void proj_v_body(
    char* smem, int bid, const float* __restrict__ X,
    const float* __restrict__ Wv, const float* __restrict__ bv,
    unsigned short* __restrict__ VtOut)
{
  char* Xs = smem;
  char* Ws = smem + 32768;

  const int tid = threadIdx.x;
  const int w = tid >> 6, lane = tid & 63, lr = lane & 15, g = lane >> 4;
  const int rb = bid >> 3, nb = bid & 7;
  const int r0 = rb * 256, d0 = nb * 64;

  f32x4 acc[4][4];
  #pragma unroll
  for (int rt = 0; rt < 4; ++rt)
    #pragma unroll
    for (int nt = 0; nt < 4; ++nt) acc[rt][nt] = f32x4{0.f, 0.f, 0.f, 0.f};

  for (int kc = 0; kc < 8; ++kc) {
    if (kc) __syncthreads();
    #pragma unroll
    for (int p = 0; p < 8; ++p) {
      int j = tid + p * 256;
      int row = j >> 3, e0 = (j & 7) * 8;
      const float* src = X + (size_t)(r0 + row) * DD + kc * 64 + e0;
      f32x4v f0 = *reinterpret_cast<const f32x4v*>(src);
      f32x4v f1 = *reinterpret_cast<const f32x4v*>(src + 4);
      u16x8 v;
      #pragma unroll
      for (int e = 0; e < 4; ++e) { v[e] = f2bf(f0[e]); v[e + 4] = f2bf(f1[e]); }
      *reinterpret_cast<u16x8*>(Xs + row * 128 + ((e0 * 2) ^ ((row & 7) << 4))) = v;
    }
    #pragma unroll
    for (int p = 0; p < 2; ++p) {
      int j = tid + p * 256;
      int n = j >> 3, e0 = (j & 7) * 8;
      const float* src = Wv + (size_t)(d0 + n) * DD + kc * 64 + e0;
      f32x4v f0 = *reinterpret_cast<const f32x4v*>(src);
      f32x4v f1 = *reinterpret_cast<const f32x4v*>(src + 4);
      u16x8 v;
      #pragma unroll
      for (int e = 0; e < 4; ++e) { v[e] = f2bf(f0[e]); v[e + 4] = f2bf(f1[e]); }
      *reinterpret_cast<u16x8*>(Ws + n * 128 + ((e0 * 2) ^ ((n & 7) << 4))) = v;
    }
    __syncthreads();
    #pragma unroll
    for (int ks = 0; ks < 2; ++ks) {
      bf16x8 a[4];
      #pragma unroll
      for (int rt = 0; rt < 4; ++rt) {
        int arow = w * 64 + rt * 16 + lr;
        a[rt] = *reinterpret_cast<const bf16x8*>(
            Xs + arow * 128 + ((ks * 64 + g * 16) ^ ((arow & 7) << 4)));
      }
      #pragma unroll
      for (int nt = 0; nt < 4; ++nt) {
        int n = nt * 16 + lr;
        bf16x8 bb = *reinterpret_cast<const bf16x8*>(
            Ws + n * 128 + ((ks * 64 + g * 16) ^ ((n & 7) << 4)));
        #pragma unroll
        for (int rt = 0; rt < 4; ++rt) acc[rt][nt] = MFMA16(a[rt], bb, acc[rt][nt]);
      }
    }
  }

  __syncthreads();
  float bias[4];
  #pragma unroll
  for (int nt = 0; nt < 4; ++nt) bias[nt] = bv[d0 + nt * 16 + lr];

  unsigned short* Ts = (unsigned short*)smem;
  #pragma unroll
  for (int rt = 0; rt < 4; ++rt)
    #pragma unroll
    for (int nt = 0; nt < 4; ++nt) {
      int dl = nt * 16 + lr;
      #pragma unroll
      for (int i = 0; i < 4; ++i) {
        int rl = w * 64 + rt * 16 + g * 4 + i;
        Ts[dl * 256 + (rl ^ ((dl & 31) << 1))] = f2bf(acc[rt][nt][i] + bias[nt]);
      }
    }
  __syncthreads();

  int bsel = tid >> 6, dl = tid & 63;
  int l0 = r0 >> 2;
  #pragma unroll
  for (int jj = 0; jj < 8; ++jj) {
    u16x8 v;
    #pragma unroll
    for (int e = 0; e < 8; ++e) {
      int rl = (jj * 8 + e) * 4 + bsel;
      v[e] = Ts[dl * 256 + (rl ^ ((dl & 31) << 1))];
    }
    *reinterpret_cast<u16x8*>(VtOut + ((size_t)(bsel * DD + d0 + dl)) * LL + l0 + jj * 8) = v;
  }
}

// ==========================================================================
// proj_all: one dispatch, grid 1024. Blocks 0..511 run the qk path (query &
// key projections), 512..1023 the v path. The two workloads are independent,
// so the CU scheduler co-fills with both -> combined time ~ max, not sum.
// ==========================================================================
__global__ __launch_bounds__(256) void proj_all_kernel(
    const float* __restrict__ Xq, const float* __restrict__ Xk,
    const float* __restrict__ Xv,
    const float* __restrict__ Wk, const float* __restrict__ bk,
    const float* __restrict__ Wv, const float* __restrict__ bv,
    unsigned short* __restrict__ Outq, unsigned short* __restrict__ Outk,
    unsigned short* __restrict__ VtOut)
{
  __shared__ char smem[49152];
  const int bid = blockIdx.x;
  if (bid < 512) {
    proj_qk_body(smem, bid, Xq, Xk, Wk, bk, Outq, Outk);
  } else {
    proj_v_body(smem, bid - 512, Xv, Wv, bv, VtOut);
  }
}

// ==========================================================================
// attn (R7, best measured: 156.8 us): v3 tiling (QBLK=64, KBLK=64, grid 256,
// 8 waves, 2/SIMD) with the barrier period as one dense MFMA window:
//   [issue K(t+2) | ds_read K(t)+P(t-1) frags | lgkm+schedbar |
//    setprio: 8 S-MFMA + 32 PV-MFMA | issue V(t+1) (2-period cover) |
//    exp + P(t) write + K(t+1) LDS write (counted vmcnt) | lgkm-only barrier]
// ==========================================================================
#define QBLK 64
#define KBLK 64
#define NIT (LL / KBLK)          // 64 steps

template<bool DOPV, bool TAIL>
__device__ __forceinline__ void attn_body(
    int tS, const unsigned short* __restrict__ Kp,
    const unsigned short* __restrict__ Vp,
    const char* kcur, char* knxt, const char* prd, char* pwr,
    const bf16x8 (&qf)[4], bf16x8 (&vst)[4][2],
    u16x8 (&kstW)[2], u16x8 (&kstL)[2],
    f32x4 (&acc)[4][4], float (&lsum)[4],
    int lr, int g, int w, int wq, int ws, int r0k, int c0k)
{
  const int tK2 = TAIL ? tS : tS + 2;   // clamped prefetch indices
  const int tV1 = TAIL ? tS : tS + 1;

  // ---- 1. issue K(t+2) -> kstL (oldest vmcnt, 2-period cover) ----
  {
    const unsigned short* src = Kp + ((size_t)(tK2 * KBLK + r0k)) * KDIM + c0k;
    kstL[0] = *reinterpret_cast<const u16x8*>(src);
    kstL[1] = *reinterpret_cast<const u16x8*>(src + 32 * KDIM);
  }

  // ---- 2. phase-A ds_reads: all 8 K(t) frags + P(t-1) frags qt0,1 ----
  bf16x8 kb[2][4];
  #pragma unroll
  for (int sch = 0; sch < 2; ++sch) {
    int sr = ws * 32 + sch * 16 + lr;
    #pragma unroll
    for (int kc = 0; kc < 4; ++kc)
      kb[sch][kc] = *reinterpret_cast<const bf16x8*>(
          kcur + sr * 256 + ((kc * 64 + g * 16) ^ ((sr & 7) << 4)));
  }
  bf16x8 pf[2][2];
  if (DOPV) {
    #pragma unroll
    for (int qt = 0; qt < 2; ++qt) {
      int q = qt * 16 + lr, swz = (q & 7) << 4;
      pf[qt][0] = *reinterpret_cast<const bf16x8*>(prd + q * 128 + ((g * 16) ^ swz));
      pf[qt][1] = *reinterpret_cast<const bf16x8*>(prd + q * 128 + ((64 + g * 16) ^ swz));
    }
  }
  __builtin_amdgcn_sched_barrier(0);
  asm volatile("s_waitcnt lgkmcnt(0)" ::: "memory");
  __builtin_amdgcn_sched_barrier(0);

  // ---- 3. cluster A: S x8 + PV(qt0,1) x16 ----
  f32x4 s0 = f32x4{0.f, 0.f, 0.f, 0.f};
  f32x4 s1 = f32x4{0.f, 0.f, 0.f, 0.f};
  __builtin_amdgcn_s_setprio(1);
  #pragma unroll
  for (int kc = 0; kc < 4; ++kc) {
    s0 = MFMA16(qf[kc], kb[0][kc], s0);
    s1 = MFMA16(qf[kc], kb[1][kc], s1);
  }
  if (DOPV) {
    #pragma unroll
    for (int qt = 0; qt < 2; ++qt)
      #pragma unroll
      for (int ch = 0; ch < 4; ++ch) {
        acc[qt][ch] = MFMA16(pf[qt][0], vst[ch][0], acc[qt][ch]);
        acc[qt][ch] = MFMA16(pf[qt][1], vst[ch][1], acc[qt][ch]);
      }
  }
  __builtin_amdgcn_s_setprio(0);

  // ---- 4. phase-B: P frags qt2,3 + PV x16 ----
  if (DOPV) {
    bf16x8 pf2[2][2];
    #pragma unroll
    for (int qt = 0; qt < 2; ++qt) {
      int q = (qt + 2) * 16 + lr, swz = (q & 7) << 4;
      pf2[qt][0] = *reinterpret_cast<const bf16x8*>(prd + q * 128 + ((g * 16) ^ swz));
      pf2[qt][1] = *reinterpret_cast<const bf16x8*>(prd + q * 128 + ((64 + g * 16) ^ swz));
    }
    __builtin_amdgcn_sched_barrier(0);
    asm volatile("s_waitcnt lgkmcnt(0)" ::: "memory");
    __builtin_amdgcn_sched_barrier(0);
    __builtin_amdgcn_s_setprio(1);
    #pragma unroll
    for (int qt = 0; qt < 2; ++qt)
      #pragma unroll
      for (int ch = 0; ch < 4; ++ch) {
        acc[qt + 2][ch] = MFMA16(pf2[qt][0], vst[ch][0], acc[qt + 2][ch]);
        acc[qt + 2][ch] = MFMA16(pf2[qt][1], vst[ch][1], acc[qt + 2][ch]);
      }
    __builtin_amdgcn_s_setprio(0);
  }

  // ---- 5. issue V(t+1) into the just-consumed set (2-period cover) ----
  #pragma unroll
  for (int ch = 0; ch < 4; ++ch)
    #pragma unroll
    for (int sc = 0; sc < 2; ++sc)
      vst[ch][sc] = *reinterpret_cast<const bf16x8*>(
          Vp + (size_t)(w * 64 + ch * 16 + lr) * LL + tV1 * KBLK + sc * 32 + g * 8);

  // ---- 6. softmax numerator (fixed max 31) + P(t) write ----
  const int sr0 = ws * 32 + lr, sr1 = sr0 + 16;
  #pragma unroll
  for (int i = 0; i < 4; ++i) {
    float p0 = exp2f(fmaf(s0[i], 43.280851f, -44.723546f));
    float p1 = exp2f(fmaf(s1[i], 43.280851f, -44.723546f));
    lsum[i] += p0 + p1;
    int q = wq * 16 + g * 4 + i, swz = (q & 7) << 4;
    *(unsigned short*)(pwr + q * 128 + ((sr0 * 2) ^ swz)) = f2bf(p0);
    *(unsigned short*)(pwr + q * 128 + ((sr1 * 2) ^ swz)) = f2bf(p1);
  }

  // ---- 7. K(t+1) regs -> other LDS buffer (counted vmcnt; V in flight) ----
  {
    int swz = (r0k & 7) << 4;
    *reinterpret_cast<u16x8*>(knxt + r0k * 256 + ((c0k * 2) ^ swz)) = kstW[0];
    *reinterpret_cast<u16x8*>(knxt + (r0k + 32) * 256 + ((c0k * 2) ^ swz)) = kstW[1];
  }
  lds_barrier();
}

__global__ __launch_bounds__(512, 2) void attn_kernel(
    const unsigned short* __restrict__ Qn, const unsigned short* __restrict__ Kn,
    const unsigned short* __restrict__ Vt, float* __restrict__ Out)
{
  __shared__ char smem[49664];
  char* Ks0 = smem;                                  // [64 s][128 k] bf16, 16KB
  char* Ks1 = smem + 16384;
  char* Ps0 = smem + 32768;                          // [64 q][64 s] bf16, 8KB
  char* Ps1 = smem + 40960;
  float* Ls = (float*)(smem + 49152);                // [2][64] partial row sums

  const int tid = threadIdx.x;
  const int w = tid >> 6, lane = tid & 63, lr = lane & 15, g = lane >> 4;
  const int wq = w & 3, ws = w >> 2;
  const int r0k = tid >> 4, c0k = (tid & 15) * 8;    // K staging mapping

  // XCD-grouping swizzle: batch b -> XCD pair {2b,2b+1} (rr dispatch)
  const int bid = blockIdx.x;
  const int b = (bid & 7) >> 1;
  const int tile = ((bid >> 3) << 1) | (bid & 1);
  const int q0 = tile * QBLK;

  const unsigned short* Kp = Kn + (size_t)b * LL * KDIM;
  const unsigned short* Vp = Vt + (size_t)b * DD * LL;

  // Q A-fragments (KD=128 -> 4 chunks of 32)
  bf16x8 qf[4];
  {
    const unsigned short* qp = Qn + ((size_t)(b * LL + q0 + wq * 16 + lr)) * KDIM + g * 8;
    #pragma unroll
    for (int kc = 0; kc < 4; ++kc)
      qf[kc] = *reinterpret_cast<const bf16x8*>(qp + kc * 32);
  }

  f32x4 acc[4][4];
  #pragma unroll
  for (int qt = 0; qt < 4; ++qt)
    #pragma unroll
    for (int ch = 0; ch < 4; ++ch) acc[qt][ch] = f32x4{0.f, 0.f, 0.f, 0.f};
  float lsum[4] = {0.f, 0.f, 0.f, 0.f};

  bf16x8 vstA[4][2], vstB[4][2];
  u16x8 kstE[2], kstO[2];

  // ---- prologue: K(0) -> Ks0 direct; V(0) -> vstA; K(1) -> kstO ----
  {
    u16x8 k0 = *reinterpret_cast<const u16x8*>(Kp + (size_t)r0k * KDIM + c0k);
    u16x8 k1 = *reinterpret_cast<const u16x8*>(Kp + (size_t)(r0k + 32) * KDIM + c0k);
    int swz = (r0k & 7) << 4;
    *reinterpret_cast<u16x8*>(Ks0 + r0k * 256 + ((c0k * 2) ^ swz)) = k0;
    *reinterpret_cast<u16x8*>(Ks0 + (r0k + 32) * 256 + ((c0k * 2) ^ swz)) = k1;
    #pragma unroll
    for (int ch = 0; ch < 4; ++ch)
      #pragma unroll
      for (int sc = 0; sc < 2; ++sc)
        vstA[ch][sc] = *reinterpret_cast<const bf16x8*>(
            Vp + (size_t)(w * 64 + ch * 16 + lr) * LL + sc * 32 + g * 8);
    const unsigned short* src = Kp + ((size_t)(1 * KBLK + r0k)) * KDIM + c0k;
    kstO[0] = *reinterpret_cast<const u16x8*>(src);
    kstO[1] = *reinterpret_cast<const u16x8*>(src + 32 * KDIM);
  }
  __syncthreads();

  // ---- body 0: S(0) only; loads K(2)->kstE, V(1)->vstB; writes K(1)->Ks1 ----
  attn_body<false, false>(0, Kp, Vp, Ks0, Ks1, Ps1, Ps0, qf, vstB, kstO, kstE,
                          acc, lsum, lr, g, w, wq, ws, r0k, c0k);

  // ---- main loop: bodies t=1..62 (odd/even name rotation) ----
  for (int t = 1; t < 63; t += 2) {
    attn_body<true, false>(t,     Kp, Vp, Ks1, Ks0, Ps0, Ps1, qf, vstA, kstE, kstO,
                           acc, lsum, lr, g, w, wq, ws, r0k, c0k);
    attn_body<true, false>(t + 1, Kp, Vp, Ks0, Ks1, Ps1, Ps0, qf, vstB, kstO, kstE,
                           acc, lsum, lr, g, w, wq, ws, r0k, c0k);
  }
  // ---- body 63 (tail: clamped prefetches) ----
  attn_body<true, true>(63, Kp, Vp, Ks1, Ks0, Ps0, Ps1, qf, vstA, kstE, kstO,
                        acc, lsum, lr, g, w, wq, ws, r0k, c0k);

  // ---- epilogue PV(63): P from Ps1, V(63) in vstB ----
  #pragma unroll
  for (int qt = 0; qt < 4; ++qt) {
    int q = qt * 16 + lr, swz = (q & 7) << 4;
    bf16x8 pa0 = *reinterpret_cast<const bf16x8*>(Ps1 + q * 128 + ((g * 16) ^ swz));
    bf16x8 pa1 = *reinterpret_cast<const bf16x8*>(Ps1 + q * 128 + ((64 + g * 16) ^ swz));
    #pragma unroll
    for (int ch = 0; ch < 4; ++ch) {
      acc[qt][ch] = MFMA16(pa0, vstB[ch][0], acc[qt][ch]);
      acc[qt][ch] = MFMA16(pa1, vstB[ch][1], acc[qt][ch]);
    }
  }

  // ---- combine partial row sums across the two s-halves ----
  #pragma unroll
  for (int m = 1; m < 16; m <<= 1) {
    #pragma unroll
    for (int i = 0; i < 4; ++i) lsum[i] += __shfl_xor(lsum[i], m);
  }
  if (lr == 0) {
    #pragma unroll
    for (int i = 0; i < 4; ++i) Ls[ws * 64 + wq * 16 + g * 4 + i] = lsum[i];
  }
  __syncthreads();

  // ---- scale by 1/l and store ----
  #pragma unroll
  for (int qt = 0; qt < 4; ++qt) {
    float linv[4];
    #pragma unroll
    for (int i = 0; i < 4; ++i) {
      int q = qt * 16 + g * 4 + i;
      linv[i] = 1.0f / (Ls[q] + Ls[64 + q]);
    }
    #pragma unroll
    for (int ch = 0; ch < 4; ++ch) {
      int d = w * 64 + ch * 16 + lr;
      #pragma unroll
      for (int i = 0; i < 4; ++i) {
        int q = q0 + qt * 16 + g * 4 + i;
        Out[((size_t)q * NB + b) * DD + d] = acc[qt][ch][i] * linv[i];
      }
    }
  }
}

// ==========================================================================
extern "C" void kernel_launch(void* const* d_in, const int* in_sizes, int n_in,
                              void* d_out, int out_size, void* d_ws, size_t ws_size,
                              hipStream_t stream) {
  const float* query = (const float*)d_in[0];
  const float* key   = (const float*)d_in[1];
  const float* value = (const float*)d_in[2];
  const float* WKw   = (const float*)d_in[3];
  const float* WKb   = (const float*)d_in[4];
  const float* WVw   = (const float*)d_in[5];
  const float* WVb   = (const float*)d_in[6];
  float* out = (float*)d_out;

  unsigned short* wqn = (unsigned short*)d_ws;            // [4][4096][128] bf16
  unsigned short* wkn = wqn + (size_t)NB * LL * KDIM;     // [4][4096][128] bf16
  unsigned short* vt  = wkn + (size_t)NB * LL * KDIM;     // [4][512][4096] bf16

  proj_all_kernel<<<1024, 256, 0, stream>>>(query, key, value,
                                            WKw, WKb, WVw, WVb,
                                            wqn, wkn, vt);
  attn_kernel<<<256, 512, 0, stream>>>(wqn, wkn, vt, out);
}